// Round 4
// baseline (458.880 us; speedup 1.0000x reference)
//
#include <hip/hip_runtime.h>

// ---------------------------------------------------------------------------
// FP_SA: fused point-transformer block, MI355X bf16 MFMA implementation.
// Token-major [tok, ch] bf16 activations. MFMA 16x16x32 bf16.
// R3: mega-fusion — 7 launches. Big LDS tiles XOR-swizzled (col ^= (row&7)*8).
// ---------------------------------------------------------------------------

typedef float f32x4 __attribute__((ext_vector_type(4)));
typedef __bf16 bf16x8 __attribute__((ext_vector_type(8)));
typedef __bf16 bf16x4 __attribute__((ext_vector_type(4)));

#define MFMA16(a, b, c) __builtin_amdgcn_mfma_f32_16x16x32_bf16((a), (b), (c), 0, 0, 0)

__device__ __forceinline__ void gll16(const __bf16* g, __bf16* l) {
    __builtin_amdgcn_global_load_lds(
        (const __attribute__((address_space(1))) void*)g,
        (__attribute__((address_space(3))) void*)l, 16, 0, 0);
}

// ---------------- prep: weights -> bf16, zero KV/Ksum ----------------------
__global__ __launch_bounds__(256) void prep_weights_kernel(
    const float* __restrict__ s0, const float* __restrict__ s1,
    const float* __restrict__ s2, const float* __restrict__ s3,
    const float* __restrict__ s4, const float* __restrict__ s5,
    const float* __restrict__ s6,
    __bf16* __restrict__ d0, __bf16* __restrict__ d1, __bf16* __restrict__ d2,
    __bf16* __restrict__ d3, __bf16* __restrict__ d4, __bf16* __restrict__ d5,
    __bf16* __restrict__ d6, float* __restrict__ zbase)
{
    int idx = blockIdx.x * 256 + threadIdx.x;
    if (idx < 327680) {                 // 5 x 65536: q_w, k_w, v_w, merge_w, pos_w2
        int seg = idx >> 16, off = idx & 65535;
        const float* s = (seg == 0) ? s0 : (seg == 1) ? s1 : (seg == 2) ? s2 : (seg == 3) ? s3 : s4;
        __bf16* d = (seg == 0) ? d0 : (seg == 1) ? d1 : (seg == 2) ? d2 : (seg == 3) ? d3 : d4;
        d[off] = (__bf16)s[off];
    } else if (idx < 589824) {          // mlp_w1: 262144
        int off = idx - 327680; d5[off] = (__bf16)s5[off];
    } else if (idx < 720896) {          // mlp_w2: 131072
        int off = idx - 589824; d6[off] = (__bf16)s6[off];
    } else if (idx < 754688) {          // zero KV (32768 f32) + Ksum (1024 f32)
        zbase[idx - 720896] = 0.f;
    }
}

// ---------------- transpose fp32 [256, T] -> bf16 [T, 256] -----------------
__global__ __launch_bounds__(256) void transpose_cast_kernel(
    const float* __restrict__ In, __bf16* __restrict__ Outb)
{
    const int tid = threadIdx.x;
    const int t0 = blockIdx.x * 64, c0 = blockIdx.y * 64;
    const size_t b = blockIdx.z;
    __shared__ __bf16 tile[64 * 72];
    #pragma unroll
    for (int i = 0; i < 4; ++i) {
        int c = i * 16 + (tid >> 4);
        int t4 = (tid & 15) * 4;
        float4 v = *(const float4*)(In + (b * 256 + c0 + c) * 16384 + t0 + t4);
        tile[(t4 + 0) * 72 + c] = (__bf16)v.x;
        tile[(t4 + 1) * 72 + c] = (__bf16)v.y;
        tile[(t4 + 2) * 72 + c] = (__bf16)v.z;
        tile[(t4 + 3) * 72 + c] = (__bf16)v.w;
    }
    __syncthreads();
    #pragma unroll
    for (int i = 0; i < 2; ++i) {
        int chunk = tid + i * 256;
        int tr = chunk >> 3, c8 = (chunk & 7) * 8;
        bf16x8 v = *(const bf16x8*)(tile + tr * 72 + c8);
        *(bf16x8*)(Outb + (b * 16384 + t0 + tr) * 256 + c0 + c8) = v;
    }
}

// ---------------- K-GEMM: K = elu(F2T @ WK^T)+1, fused Ksum ----------------
__global__ __launch_bounds__(256, 4) void kgemm_kernel(
    const __bf16* __restrict__ Wg, const __bf16* __restrict__ A0,
    __bf16* __restrict__ Outg, float* __restrict__ KSg)
{
    const int tid = threadIdx.x, w = tid >> 6, l = tid & 63, lm = l & 15;
    const int gm0 = blockIdx.x * 128, gn0 = blockIdx.y * 128;
    const size_t b = blockIdx.z;
    const __bf16* A0b = A0 + b * 16384 * (size_t)256;
    __bf16* Outb = Outg + b * 16384 * (size_t)256;

    __shared__ __bf16 Alds[2][128 * 32];
    __shared__ __bf16 Wlds[2][128 * 32];
    __shared__ float kred[16 * 64];

    f32x4 acc[4][4];
    #pragma unroll
    for (int i = 0; i < 4; ++i)
        #pragma unroll
        for (int j = 0; j < 4; ++j) acc[i][j] = (f32x4){0.f, 0.f, 0.f, 0.f};

    const int wm = (w >> 1) * 64, wn = (w & 1) * 64;
    const int srow = tid >> 2, scol = (tid & 3) * 8;
    const int koff = (l >> 4) * 8;
    const int wbase = w * 512;

    auto stage = [&](int buf, int ks) {
        gll16(A0b + (size_t)(gm0 + srow) * 256 + ks + scol,      &Alds[buf][wbase]);
        gll16(A0b + (size_t)(gm0 + 64 + srow) * 256 + ks + scol, &Alds[buf][2048 + wbase]);
        gll16(Wg + (size_t)(gn0 + srow) * 256 + ks + scol,       &Wlds[buf][wbase]);
        gll16(Wg + (size_t)(gn0 + 64 + srow) * 256 + ks + scol,  &Wlds[buf][2048 + wbase]);
    };
    stage(0, 0);
    __syncthreads();
    int cur = 0;
    for (int ks = 0; ks < 256; ks += 32) {
        if (ks + 32 < 256) stage(cur ^ 1, ks + 32);
        bf16x8 af[4], wf[4];
        #pragma unroll
        for (int mf = 0; mf < 4; ++mf)
            af[mf] = *(const bf16x8*)&Alds[cur][(wm + mf * 16 + lm) * 32 + koff];
        #pragma unroll
        for (int nf = 0; nf < 4; ++nf)
            wf[nf] = *(const bf16x8*)&Wlds[cur][(wn + nf * 16 + lm) * 32 + koff];
        #pragma unroll
        for (int mf = 0; mf < 4; ++mf)
            #pragma unroll
            for (int nf = 0; nf < 4; ++nf)
                acc[mf][nf] = MFMA16(af[mf], wf[nf], acc[mf][nf]);
        __syncthreads();
        cur ^= 1;
    }

    const int r0 = (l >> 4) * 4;
    float kpart[4] = {0.f, 0.f, 0.f, 0.f};
    #pragma unroll
    for (int mf = 0; mf < 4; ++mf) {
        #pragma unroll
        for (int nf = 0; nf < 4; ++nf) {
            int tok = gm0 + wm + mf * 16 + r0;
            int ch  = gn0 + wn + nf * 16 + lm;
            #pragma unroll
            for (int r = 0; r < 4; ++r) {
                float v = acc[mf][nf][r];
                v = (v > 0.f) ? (v + 1.f) : __expf(v);   // elu(x)+1
                kpart[nf] += v;
                Outb[(size_t)(tok + r) * 256 + ch] = (__bf16)v;
            }
        }
    }
    #pragma unroll
    for (int nf = 0; nf < 4; ++nf)
        kred[(w * 4 + (l >> 4)) * 64 + nf * 16 + lm] = kpart[nf];
    __syncthreads();
    if (tid < 128) {
        int c = tid;
        int wsel = (c >= 64) ? 1 : 0;
        float s = 0.f;
        #pragma unroll
        for (int q = 0; q < 4; ++q)
            s += kred[((wsel * 4) + q) * 64 + (c & 63)]
               + kred[(((wsel + 2) * 4) + q) * 64 + (c & 63)];
        atomicAdd(&KSg[b * 256 + gn0 + c], s);
    }
}

// ---- fuse_pv: pos-hidden (in-reg) + pos-GEMM + residual + V-GEMM ----------
// block: 128 tokens, 512 threads (8 waves in 2x4 grid, wave tile 64tok x 64ch)
__global__ __launch_bounds__(512, 1) void fuse_pv(
    const float* __restrict__ xyz2, const float* __restrict__ pw1g,
    const float* __restrict__ pb1g, const __bf16* __restrict__ WP2,
    const float* __restrict__ pb2g, const __bf16* __restrict__ F2Tg,
    const __bf16* __restrict__ WVg, __bf16* __restrict__ VBg)
{
    const int tid = threadIdx.x, w = tid >> 6, l = tid & 63, lm = l & 15;
    const int tok0 = blockIdx.x * 128;
    const size_t b = blockIdx.y;
    const int wtm = w >> 2, wtn = w & 3;
    const int koff = (l >> 4) * 8, r0 = (l >> 4) * 4;

    __shared__ __bf16 tile[128 * 256];       // F2T -> F2P, swizzled
    __shared__ __bf16 wstage[2][256 * 32];
    __shared__ float pw1[256 * 4];
    __shared__ float pb1[256], pb2[256];

    if (tid < 256) {
        pw1[tid * 4 + 0] = pw1g[tid * 3 + 0];
        pw1[tid * 4 + 1] = pw1g[tid * 3 + 1];
        pw1[tid * 4 + 2] = pw1g[tid * 3 + 2];
        pb1[tid] = pb1g[tid];
        pb2[tid] = pb2g[tid];
    }
    // F2T tile, swizzled source -> linear LDS (read back with same XOR)
    const __bf16* F2Tb = F2Tg + ((size_t)b * 16384 + tok0) * 256;
    #pragma unroll
    for (int i = 0; i < 8; ++i) {
        int row = i * 16 + w * 2 + (l >> 5);
        int col = ((l & 31) * 8) ^ ((row & 7) * 8);
        gll16(F2Tb + (size_t)row * 256 + col, tile + i * 4096 + w * 512 + (l & 31) * 8);
    }
    // xyz for this lane's 4 token rows
    float xr[4], yr[4], zr[4];
    #pragma unroll
    for (int mf = 0; mf < 4; ++mf) {
        size_t tg = (size_t)b * 16384 + tok0 + wtm * 64 + mf * 16 + lm;
        xr[mf] = xyz2[tg * 3 + 0]; yr[mf] = xyz2[tg * 3 + 1]; zr[mf] = xyz2[tg * 3 + 2];
    }

    auto stageW = [&](int buf, const __bf16* Wsrc, int ks) {
        #pragma unroll
        for (int j = 0; j < 2; ++j)
            gll16(Wsrc + (size_t)(j * 128 + (tid >> 2)) * 256 + ks + (tid & 3) * 8,
                  &wstage[buf][j * 4096 + tid * 8]);
    };

    // ---- chain1: P = hidden @ WP2^T (hidden computed in-register) ----
    f32x4 acc[4][4];
    #pragma unroll
    for (int i = 0; i < 4; ++i)
        #pragma unroll
        for (int j = 0; j < 4; ++j) acc[i][j] = (f32x4){0.f, 0.f, 0.f, 0.f};
    stageW(0, WP2, 0);
    __syncthreads();
    int cur = 0;
    for (int ks = 0; ks < 256; ks += 32) {
        if (ks + 32 < 256) stageW(cur ^ 1, WP2, ks + 32);
        bf16x8 af[4];
        #pragma unroll
        for (int mf = 0; mf < 4; ++mf)
            #pragma unroll
            for (int j = 0; j < 8; ++j) {
                int k = ks + koff + j;
                float h = fmaf(xr[mf], pw1[k * 4],
                          fmaf(yr[mf], pw1[k * 4 + 1],
                          fmaf(zr[mf], pw1[k * 4 + 2], pb1[k])));
                af[mf][j] = (__bf16)fmaxf(h, 0.f);
            }
        bf16x8 wf[4];
        #pragma unroll
        for (int nf = 0; nf < 4; ++nf)
            wf[nf] = *(const bf16x8*)&wstage[cur][(wtn * 64 + nf * 16 + lm) * 32 + koff];
        #pragma unroll
        for (int mf = 0; mf < 4; ++mf)
            #pragma unroll
            for (int nf = 0; nf < 4; ++nf)
                acc[mf][nf] = MFMA16(af[mf], wf[nf], acc[mf][nf]);
        __syncthreads();
        cur ^= 1;
    }
    // epilogue1: F2P = P + pb2 + F2T (in-place RMW, per-element owner)
    stageW(0, WVg, 0);   // prefetch V weights under the epilogue
    #pragma unroll
    for (int mf = 0; mf < 4; ++mf)
        #pragma unroll
        for (int nf = 0; nf < 4; ++nf) {
            int ch = wtn * 64 + nf * 16 + lm;
            #pragma unroll
            for (int r = 0; r < 4; ++r) {
                int tl = wtm * 64 + mf * 16 + r0 + r;
                int addr = tl * 256 + (ch ^ ((tl & 7) * 8));
                float v = acc[mf][nf][r] + pb2[ch] + (float)tile[addr];
                tile[addr] = (__bf16)v;
            }
        }
    __syncthreads();

    // ---- chain2: V = F2P @ WV^T ----
    f32x4 acc2[4][4];
    #pragma unroll
    for (int i = 0; i < 4; ++i)
        #pragma unroll
        for (int j = 0; j < 4; ++j) acc2[i][j] = (f32x4){0.f, 0.f, 0.f, 0.f};
    cur = 0;
    for (int ks = 0; ks < 256; ks += 32) {
        if (ks + 32 < 256) stageW(cur ^ 1, WVg, ks + 32);
        bf16x8 af[4], wf[4];
        #pragma unroll
        for (int mf = 0; mf < 4; ++mf) {
            int row = wtm * 64 + mf * 16 + lm;
            af[mf] = *(const bf16x8*)&tile[row * 256 + ((ks + koff) ^ ((lm & 7) * 8))];
        }
        #pragma unroll
        for (int nf = 0; nf < 4; ++nf)
            wf[nf] = *(const bf16x8*)&wstage[cur][(wtn * 64 + nf * 16 + lm) * 32 + koff];
        #pragma unroll
        for (int mf = 0; mf < 4; ++mf)
            #pragma unroll
            for (int nf = 0; nf < 4; ++nf)
                acc2[mf][nf] = MFMA16(af[mf], wf[nf], acc2[mf][nf]);
        __syncthreads();
        cur ^= 1;
    }
    __bf16* VBb = VBg + ((size_t)b * 16384 + tok0) * 256;
    #pragma unroll
    for (int mf = 0; mf < 4; ++mf)
        #pragma unroll
        for (int nf = 0; nf < 4; ++nf) {
            int ch = wtn * 64 + nf * 16 + lm;
            #pragma unroll
            for (int r = 0; r < 4; ++r) {
                int tl = wtm * 64 + mf * 16 + r0 + r;
                VBb[(size_t)tl * 256 + ch] = (__bf16)acc2[mf][nf][r];
            }
        }
}

// ---------------- KV[b,h,d,e] = sum_s K[s,hd] * v[s,he] --------------------
__global__ __launch_bounds__(256) void kv_kernel(
    const __bf16* __restrict__ Kb, const __bf16* __restrict__ Vb,
    float* __restrict__ KVg)
{
    const int tid = threadIdx.x, w = tid >> 6, l = tid & 63, lm = l & 15;
    const int sc = blockIdx.x, h = blockIdx.y, b = blockIdx.z;
    __shared__ __bf16 kT[32 * 264];
    __shared__ __bf16 vT[32 * 264];
    __shared__ float red[4 * 32 * 32];

    f32x4 acc[2][2];
    #pragma unroll
    for (int i = 0; i < 2; ++i)
        #pragma unroll
        for (int j = 0; j < 2; ++j) acc[i][j] = (f32x4){0.f, 0.f, 0.f, 0.f};

    const int koff = (l >> 4) * 8, r0 = (l >> 4) * 4;
    const size_t rowbase = (size_t)b * 16384;
    bf16x4 kreg[8], vreg[8];
    auto loadsub = [&](int sub) {
        int s0 = sc * 1024 + sub * 256;
        #pragma unroll
        for (int pass = 0; pass < 8; ++pass) {
            int sl = pass * 32 + (tid >> 3);
            int c4 = (tid & 7) * 4;
            kreg[pass] = *(const bf16x4*)(Kb + (rowbase + s0 + sl) * 256 + h * 32 + c4);
            vreg[pass] = *(const bf16x4*)(Vb + (rowbase + s0 + sl) * 256 + h * 32 + c4);
        }
    };
    loadsub(0);
    for (int sub = 0; sub < 4; ++sub) {
        __syncthreads();
        #pragma unroll
        for (int pass = 0; pass < 8; ++pass) {
            int sl = pass * 32 + (tid >> 3);
            int c4 = (tid & 7) * 4;
            #pragma unroll
            for (int i = 0; i < 4; ++i) {
                kT[(c4 + i) * 264 + sl] = kreg[pass][i];
                vT[(c4 + i) * 264 + sl] = vreg[pass][i];
            }
        }
        __syncthreads();
        if (sub < 3) loadsub(sub + 1);
        #pragma unroll
        for (int kq = 0; kq < 2; ++kq) {
            int sb = w * 64 + kq * 32;
            bf16x8 af[2], bfr[2];
            #pragma unroll
            for (int mf = 0; mf < 2; ++mf)
                af[mf] = *(const bf16x8*)(kT + (mf * 16 + lm) * 264 + sb + koff);
            #pragma unroll
            for (int nf = 0; nf < 2; ++nf)
                bfr[nf] = *(const bf16x8*)(vT + (nf * 16 + lm) * 264 + sb + koff);
            #pragma unroll
            for (int mf = 0; mf < 2; ++mf)
                #pragma unroll
                for (int nf = 0; nf < 2; ++nf)
                    acc[mf][nf] = MFMA16(af[mf], bfr[nf], acc[mf][nf]);
        }
    }
    #pragma unroll
    for (int mf = 0; mf < 2; ++mf)
        #pragma unroll
        for (int nf = 0; nf < 2; ++nf)
            #pragma unroll
            for (int r = 0; r < 4; ++r) {
                int d = mf * 16 + r0 + r, e = nf * 16 + lm;
                red[w * 1024 + d * 32 + e] = acc[mf][nf][r];
            }
    __syncthreads();
    #pragma unroll
    for (int i = 0; i < 4; ++i) {
        int idx = tid + i * 256;
        float s = red[idx] + red[1024 + idx] + red[2048 + idx] + red[3072 + idx];
        atomicAdd(&KVg[((size_t)(b * 8 + h)) * 1024 + idx], s);
    }
}

// ---- qattn: Q-GEMM + Z + msg-MFMA + merge-GEMM + LN1 ----------------------
// block: 128 tokens, 512 threads (2x4 wave grid, wave tile 64tok x 64ch)
__global__ __launch_bounds__(512, 1) void qattn(
    const __bf16* __restrict__ F1Tg, const __bf16* __restrict__ WQg,
    const float* __restrict__ KVg, const float* __restrict__ KSg,
    const __bf16* __restrict__ WMg, const float* __restrict__ g1,
    const float* __restrict__ b1, __bf16* __restrict__ MSG1g)
{
    const int tid = threadIdx.x, w = tid >> 6, l = tid & 63, lm = l & 15;
    const int tok0 = blockIdx.x * 128;
    const size_t b = blockIdx.y;
    const int wtm = w >> 2, wtn = w & 3;
    const int koff = (l >> 4) * 8, r0 = (l >> 4) * 4;

    __shared__ __bf16 qtile[128 * 256];      // Q then msg, swizzled
    __shared__ __bf16 astage[2][128 * 32];
    __shared__ __bf16 wstage[2][256 * 32];
    __shared__ __bf16 kvT[8 * 32 * 40];      // [h][e][d]
    __shared__ float ks_lds[256], z_lds[128 * 8];
    __shared__ float red1[4][128], red2[4][128], mu_lds[128], rs_lds[128];
    __shared__ float g_lds[256], b_lds[256];

    if (tid < 256) {
        ks_lds[tid] = KSg[b * 256 + tid];
        g_lds[tid] = g1[tid];
        b_lds[tid] = b1[tid];
    }
    const float* KVb = KVg + b * 8192;
    #pragma unroll
    for (int i = 0; i < 16; ++i) {
        int idx = tid + i * 512;
        int h = idx >> 10, d = (idx >> 5) & 31, e = idx & 31;
        kvT[(h * 32 + e) * 40 + d] = (__bf16)KVb[idx];
    }

    const __bf16* F1Tb = F1Tg + ((size_t)b * 16384 + tok0) * 256;
    auto stageA = [&](int buf, int ks) {
        gll16(F1Tb + (size_t)(tid >> 2) * 256 + ks + (tid & 3) * 8, &astage[buf][tid * 8]);
    };
    auto stageW = [&](int buf, const __bf16* Wsrc, int ks) {
        #pragma unroll
        for (int j = 0; j < 2; ++j)
            gll16(Wsrc + (size_t)(j * 128 + (tid >> 2)) * 256 + ks + (tid & 3) * 8,
                  &wstage[buf][j * 4096 + tid * 8]);
    };

    // ---- chain1: Q = elu(F1T @ WQ^T) + 1 ----
    f32x4 acc[4][4];
    #pragma unroll
    for (int i = 0; i < 4; ++i)
        #pragma unroll
        for (int j = 0; j < 4; ++j) acc[i][j] = (f32x4){0.f, 0.f, 0.f, 0.f};
    stageA(0, 0); stageW(0, WQg, 0);
    __syncthreads();
    int cur = 0;
    for (int ks = 0; ks < 256; ks += 32) {
        if (ks + 32 < 256) { stageA(cur ^ 1, ks + 32); stageW(cur ^ 1, WQg, ks + 32); }
        bf16x8 af[4], wf[4];
        #pragma unroll
        for (int mf = 0; mf < 4; ++mf)
            af[mf] = *(const bf16x8*)&astage[cur][(wtm * 64 + mf * 16 + lm) * 32 + koff];
        #pragma unroll
        for (int nf = 0; nf < 4; ++nf)
            wf[nf] = *(const bf16x8*)&wstage[cur][(wtn * 64 + nf * 16 + lm) * 32 + koff];
        #pragma unroll
        for (int mf = 0; mf < 4; ++mf)
            #pragma unroll
            for (int nf = 0; nf < 4; ++nf)
                acc[mf][nf] = MFMA16(af[mf], wf[nf], acc[mf][nf]);
        __syncthreads();
        cur ^= 1;
    }
    stageW(0, WMg, 0);   // prefetch merge weights early
    #pragma unroll
    for (int mf = 0; mf < 4; ++mf)
        #pragma unroll
        for (int nf = 0; nf < 4; ++nf) {
            int ch = wtn * 64 + nf * 16 + lm;
            #pragma unroll
            for (int r = 0; r < 4; ++r) {
                int tl = wtm * 64 + mf * 16 + r0 + r;
                float v = acc[mf][nf][r];
                v = (v > 0.f) ? (v + 1.f) : __expf(v);
                qtile[tl * 256 + (ch ^ ((tl & 7) * 8))] = (__bf16)v;
            }
        }
    __syncthreads();

    // ---- Z[tok,h] = 1 / (Q . Ksum + eps) ----
    #pragma unroll
    for (int i = 0; i < 2; ++i) {
        int p = tid + i * 512;
        int tok = p >> 3, h = p & 7;
        float s = 0.f;
        #pragma unroll
        for (int d = 0; d < 32; ++d)
            s += (float)qtile[tok * 256 + ((h * 32 + d) ^ ((tok & 7) * 8))] * ks_lds[h * 32 + d];
        z_lds[tok * 8 + h] = 1.f / (s + 1e-6f);
    }
    __syncthreads();

    // ---- chain2: msg = (Q @ KV_h) * Z (2 heads per wave) ----
    f32x4 macc[4][4];
    const f32x4 zero4 = (f32x4){0.f, 0.f, 0.f, 0.f};
    #pragma unroll
    for (int hh = 0; hh < 2; ++hh) {
        int h = wtn * 2 + hh;
        bf16x8 af[4], wf[2];
        #pragma unroll
        for (int mf = 0; mf < 4; ++mf) {
            int row = wtm * 64 + mf * 16 + lm;
            af[mf] = *(const bf16x8*)&qtile[row * 256 + ((h * 32 + koff) ^ ((lm & 7) * 8))];
        }
        #pragma unroll
        for (int nf = 0; nf < 2; ++nf)
            wf[nf] = *(const bf16x8*)&kvT[(h * 32 + nf * 16 + lm) * 40 + koff];
        #pragma unroll
        for (int mf = 0; mf < 4; ++mf)
            #pragma unroll
            for (int nf = 0; nf < 2; ++nf)
                macc[mf][hh * 2 + nf] = MFMA16(af[mf], wf[nf], zero4);
    }
    __syncthreads();   // all Q reads done before overwriting with msg
    #pragma unroll
    for (int mf = 0; mf < 4; ++mf)
        #pragma unroll
        for (int hh = 0; hh < 2; ++hh)
            #pragma unroll
            for (int nf = 0; nf < 2; ++nf) {
                int h = wtn * 2 + hh;
                int ch = wtn * 64 + hh * 32 + nf * 16 + lm;
                #pragma unroll
                for (int r = 0; r < 4; ++r) {
                    int tl = wtm * 64 + mf * 16 + r0 + r;
                    float v = macc[mf][hh * 2 + nf][r] * z_lds[tl * 8 + h];
                    qtile[tl * 256 + (ch ^ ((tl & 7) * 8))] = (__bf16)v;
                }
            }
    __syncthreads();

    // ---- chain3: msg1 = LN1(msg @ WM^T) ----
    f32x4 acc3[4][4];
    #pragma unroll
    for (int i = 0; i < 4; ++i)
        #pragma unroll
        for (int j = 0; j < 4; ++j) acc3[i][j] = (f32x4){0.f, 0.f, 0.f, 0.f};
    cur = 0;
    for (int ks = 0; ks < 256; ks += 32) {
        if (ks + 32 < 256) stageW(cur ^ 1, WMg, ks + 32);
        bf16x8 af[4], wf[4];
        #pragma unroll
        for (int mf = 0; mf < 4; ++mf) {
            int row = wtm * 64 + mf * 16 + lm;
            af[mf] = *(const bf16x8*)&qtile[row * 256 + ((ks + koff) ^ ((lm & 7) * 8))];
        }
        #pragma unroll
        for (int nf = 0; nf < 4; ++nf)
            wf[nf] = *(const bf16x8*)&wstage[cur][(wtn * 64 + nf * 16 + lm) * 32 + koff];
        #pragma unroll
        for (int mf = 0; mf < 4; ++mf)
            #pragma unroll
            for (int nf = 0; nf < 4; ++nf)
                acc3[mf][nf] = MFMA16(af[mf], wf[nf], acc3[mf][nf]);
        __syncthreads();
        cur ^= 1;
    }
    #pragma unroll
    for (int mf = 0; mf < 4; ++mf)
        #pragma unroll
        for (int r = 0; r < 4; ++r) {
            float s1 = 0.f, s2 = 0.f;
            #pragma unroll
            for (int nf = 0; nf < 4; ++nf) { float v = acc3[mf][nf][r]; s1 += v; s2 += v * v; }
            #pragma unroll
            for (int m = 1; m < 16; m <<= 1) { s1 += __shfl_xor(s1, m, 64); s2 += __shfl_xor(s2, m, 64); }
            if (lm == 0) {
                int row = wtm * 64 + mf * 16 + r0 + r;
                red1[wtn][row] = s1;
                red2[wtn][row] = s2;
            }
        }
    __syncthreads();
    if (tid < 128) {
        float s1 = red1[0][tid] + red1[1][tid] + red1[2][tid] + red1[3][tid];
        float s2 = red2[0][tid] + red2[1][tid] + red2[2][tid] + red2[3][tid];
        float mu = s1 * (1.f / 256.f);
        mu_lds[tid] = mu;
        rs_lds[tid] = rsqrtf(s2 * (1.f / 256.f) - mu * mu + 1e-5f);
    }
    __syncthreads();
    __bf16* Mb = MSG1g + ((size_t)b * 16384 + tok0) * 256;
    #pragma unroll
    for (int mf = 0; mf < 4; ++mf)
        #pragma unroll
        for (int nf = 0; nf < 4; ++nf) {
            int ch = wtn * 64 + nf * 16 + lm;
            #pragma unroll
            for (int r = 0; r < 4; ++r) {
                int tl = wtm * 64 + mf * 16 + r0 + r;
                float y = (acc3[mf][nf][r] - mu_lds[tl]) * rs_lds[tl] * g_lds[ch] + b_lds[ch];
                Mb[(size_t)tl * 256 + ch] = (__bf16)y;
            }
        }
}

// ---- mlp_fused: h1 = relu([F1T,MSG1] @ W1^T); out = LN2(h1 @ W2^T), TRANS -
// block: 64 tokens, 512 threads (2x4 wave grid)
__global__ __launch_bounds__(512, 1) void mlp_fused(
    const __bf16* __restrict__ F1Tg, const __bf16* __restrict__ MSG1g,
    const __bf16* __restrict__ W1g, const __bf16* __restrict__ W2g,
    const float* __restrict__ g2, const float* __restrict__ b2,
    float* __restrict__ Outg)
{
    const int tid = threadIdx.x, w = tid >> 6, l = tid & 63, lm = l & 15;
    const int tok0 = blockIdx.x * 64;
    const size_t b = blockIdx.y;
    const int wtm = w >> 2, wtn = w & 3;
    const int koff = (l >> 4) * 8, r0 = (l >> 4) * 4;

    __shared__ __bf16 h1[64 * 512];              // 64KB, swizzled
    __shared__ __bf16 astage[2][64 * 32];        // 8KB
    __shared__ __align__(16) char wsmem[65536];  // W dbuf, then out bounce
    __bf16* wstage0 = (__bf16*)wsmem;            // [512*32]
    __bf16* wstage1 = (__bf16*)(wsmem + 32768);
    __shared__ float red1[4][64], red2[4][64], mu_lds[64], rs_lds[64];
    __shared__ float g_lds[256], b_lds[256];

    if (tid < 256) { g_lds[tid] = g2[tid]; b_lds[tid] = b2[tid]; }

    const __bf16* F1Tb  = F1Tg  + ((size_t)b * 16384 + tok0) * 256;
    const __bf16* MSG1b = MSG1g + ((size_t)b * 16384 + tok0) * 256;

    auto stageA = [&](int buf, int ks) {
        if (tid < 256) {
            const __bf16* src = (ks < 256) ? F1Tb : MSG1b;
            int kk = ks & 255;
            gll16(src + (size_t)(tid >> 2) * 256 + kk + (tid & 3) * 8, &astage[buf][tid * 8]);
        }
    };
    auto stageW1 = [&](int buf, int ks) {
        __bf16* dst = buf ? wstage1 : wstage0;
        #pragma unroll
        for (int i = 0; i < 4; ++i)
            gll16(W1g + (size_t)(i * 128 + (tid >> 2)) * 512 + ks + (tid & 3) * 8,
                  dst + i * 4096 + tid * 8);
    };
    auto stageW2 = [&](int buf, int ks) {
        __bf16* dst = buf ? wstage1 : wstage0;
        #pragma unroll
        for (int i = 0; i < 2; ++i)
            gll16(W2g + (size_t)(i * 128 + (tid >> 2)) * 512 + ks + (tid & 3) * 8,
                  dst + i * 4096 + tid * 8);
    };

    // ---- chain1: h1 = relu([F1T|MSG1] @ W1^T), wave tile 32tok x 128ch ----
    f32x4 acc[2][8];
    #pragma unroll
    for (int i = 0; i < 2; ++i)
        #pragma unroll
        for (int j = 0; j < 8; ++j) acc[i][j] = (f32x4){0.f, 0.f, 0.f, 0.f};
    stageA(0, 0); stageW1(0, 0);
    __syncthreads();
    int cur = 0;
    for (int ks = 0; ks < 512; ks += 32) {
        if (ks + 32 < 512) { stageA(cur ^ 1, ks + 32); stageW1(cur ^ 1, ks + 32); }
        __bf16* wst = cur ? wstage1 : wstage0;
        bf16x8 af[2], wf[8];
        #pragma unroll
        for (int mf = 0; mf < 2; ++mf)
            af[mf] = *(const bf16x8*)&astage[cur][(wtm * 32 + mf * 16 + lm) * 32 + koff];
        #pragma unroll
        for (int nf = 0; nf < 8; ++nf)
            wf[nf] = *(const bf16x8*)(wst + (wtn * 128 + nf * 16 + lm) * 32 + koff);
        #pragma unroll
        for (int mf = 0; mf < 2; ++mf)
            #pragma unroll
            for (int nf = 0; nf < 8; ++nf)
                acc[mf][nf] = MFMA16(af[mf], wf[nf], acc[mf][nf]);
        __syncthreads();
        cur ^= 1;
    }
    stageW2(0, 0);   // prefetch W2 under epilogue
    #pragma unroll
    for (int mf = 0; mf < 2; ++mf)
        #pragma unroll
        for (int nf = 0; nf < 8; ++nf) {
            int ch = wtn * 128 + nf * 16 + lm;
            #pragma unroll
            for (int r = 0; r < 4; ++r) {
                int tl = wtm * 32 + mf * 16 + r0 + r;
                float v = fmaxf(acc[mf][nf][r], 0.f);
                h1[tl * 512 + (ch ^ ((tl & 7) * 8))] = (__bf16)v;
            }
        }
    __syncthreads();

    // ---- chain2: out = h1 @ W2^T, wave tile 32tok x 64ch ----
    f32x4 acc2[2][4];
    #pragma unroll
    for (int i = 0; i < 2; ++i)
        #pragma unroll
        for (int j = 0; j < 4; ++j) acc2[i][j] = (f32x4){0.f, 0.f, 0.f, 0.f};
    cur = 0;
    for (int ks = 0; ks < 512; ks += 32) {
        if (ks + 32 < 512) stageW2(cur ^ 1, ks + 32);
        __bf16* wst = cur ? wstage1 : wstage0;
        bf16x8 af[2], wf[4];
        #pragma unroll
        for (int mf = 0; mf < 2; ++mf) {
            int row = wtm * 32 + mf * 16 + lm;
            af[mf] = *(const bf16x8*)&h1[row * 512 + ((ks + koff) ^ ((lm & 7) * 8))];
        }
        #pragma unroll
        for (int nf = 0; nf < 4; ++nf)
            wf[nf] = *(const bf16x8*)(wst + (wtn * 64 + nf * 16 + lm) * 32 + koff);
        #pragma unroll
        for (int mf = 0; mf < 2; ++mf)
            #pragma unroll
            for (int nf = 0; nf < 4; ++nf)
                acc2[mf][nf] = MFMA16(af[mf], wf[nf], acc2[mf][nf]);
        __syncthreads();
        cur ^= 1;
    }
    // LN2 stats
    #pragma unroll
    for (int mf = 0; mf < 2; ++mf)
        #pragma unroll
        for (int r = 0; r < 4; ++r) {
            float s1 = 0.f, s2 = 0.f;
            #pragma unroll
            for (int nf = 0; nf < 4; ++nf) { float v = acc2[mf][nf][r]; s1 += v; s2 += v * v; }
            #pragma unroll
            for (int m = 1; m < 16; m <<= 1) { s1 += __shfl_xor(s1, m, 64); s2 += __shfl_xor(s2, m, 64); }
            if (lm == 0) {
                int row = wtm * 32 + mf * 16 + r0 + r;
                red1[wtn][row] = s1;
                red2[wtn][row] = s2;
            }
        }
    __syncthreads();
    if (tid < 64) {
        float s1 = red1[0][tid] + red1[1][tid] + red1[2][tid] + red1[3][tid];
        float s2 = red2[0][tid] + red2[1][tid] + red2[2][tid] + red2[3][tid];
        float mu = s1 * (1.f / 256.f);
        mu_lds[tid] = mu;
        rs_lds[tid] = rsqrtf(s2 * (1.f / 256.f) - mu * mu + 1e-5f);
    }
    __syncthreads();
    // transposed store via padded LDS bounce: two 128-channel halves
    float* bounce = (float*)wsmem;   // [128][68] f32 = 34.8KB
    #pragma unroll
    for (int half = 0; half < 2; ++half) {
        if ((wtn >> 1) == half) {
            #pragma unroll
            for (int mf = 0; mf < 2; ++mf)
                #pragma unroll
                for (int nf = 0; nf < 4; ++nf) {
                    int chl = (wtn & 1) * 64 + nf * 16 + lm;
                    int ch  = half * 128 + chl;
                    #pragma unroll
                    for (int r = 0; r < 4; ++r) {
                        int tl = wtm * 32 + mf * 16 + r0 + r;
                        bounce[chl * 68 + tl] =
                            (acc2[mf][nf][r] - mu_lds[tl]) * rs_lds[tl] * g_lds[ch] + b_lds[ch];
                    }
                }
        }
        __syncthreads();
        {
            int row = tid >> 2, seg = tid & 3;
            float* src = bounce + row * 68 + seg * 16;
            float* dst = Outg + ((size_t)b * 256 + half * 128 + row) * 16384 + tok0 + seg * 16;
            #pragma unroll
            for (int j = 0; j < 4; ++j)
                *(f32x4*)(dst + j * 4) = *(const f32x4*)(src + j * 4);
        }
        __syncthreads();
    }
}

// ---------------------------------------------------------------------------
extern "C" void kernel_launch(void* const* d_in, const int* in_sizes, int n_in,
                              void* d_out, int out_size, void* d_ws, size_t ws_size,
                              hipStream_t stream) {
    const float* feat1   = (const float*)d_in[0];
    const float* feat2   = (const float*)d_in[2];
    const float* xyz2    = (const float*)d_in[3];
    const float* pos_w1  = (const float*)d_in[4];
    const float* pos_b1  = (const float*)d_in[5];
    const float* pos_w2  = (const float*)d_in[6];
    const float* pos_b2  = (const float*)d_in[7];
    const float* q_w     = (const float*)d_in[8];
    const float* k_w     = (const float*)d_in[9];
    const float* v_w     = (const float*)d_in[10];
    const float* merge_w = (const float*)d_in[11];
    const float* mlp_w1  = (const float*)d_in[12];
    const float* mlp_w2  = (const float*)d_in[13];
    const float* ln1_g   = (const float*)d_in[14];
    const float* ln1_b   = (const float*)d_in[15];
    const float* ln2_g   = (const float*)d_in[16];
    const float* ln2_b   = (const float*)d_in[17];
    float* outp = (float*)d_out;

    char* ws = (char*)d_ws;
    size_t off = 0;
    auto alloc = [&](size_t bytes) { char* p = ws + off; off += (bytes + 255) & ~(size_t)255; return p; };
    const size_t ACT = (size_t)4 * 16384 * 256 * 2;
    __bf16* WQ  = (__bf16*)alloc(65536 * 2);
    __bf16* WK  = (__bf16*)alloc(65536 * 2);
    __bf16* WV  = (__bf16*)alloc(65536 * 2);
    __bf16* WM  = (__bf16*)alloc(65536 * 2);
    __bf16* WP2 = (__bf16*)alloc(65536 * 2);
    __bf16* W1  = (__bf16*)alloc(262144 * 2);
    __bf16* W2  = (__bf16*)alloc(131072 * 2);
    float*  KV  = (float*)alloc(4 * 8 * 32 * 32 * 4);  // zeroed each call (with KS)
    float*  KS  = (float*)alloc(4 * 256 * 4);
    __bf16* F1T = (__bf16*)alloc(ACT);
    __bf16* F2T = (__bf16*)alloc(ACT);
    __bf16* KB  = (__bf16*)alloc(ACT);
    __bf16* VB  = (__bf16*)alloc(ACT);
    __bf16* MSG1 = (__bf16*)alloc(ACT);
    if (ws_size < off) return;

    // 1. weights -> bf16, zero KV/Ksum
    prep_weights_kernel<<<2948, 256, 0, stream>>>(q_w, k_w, v_w, merge_w, pos_w2,
                                                  mlp_w1, mlp_w2,
                                                  WQ, WK, WV, WM, WP2, W1, W2, KV);
    // 2/3. transpose feat1, feat2 to token-major bf16
    transpose_cast_kernel<<<dim3(256, 4, 4), 256, 0, stream>>>(feat1, F1T);
    transpose_cast_kernel<<<dim3(256, 4, 4), 256, 0, stream>>>(feat2, F2T);
    // 4. V = (F2T + posMLP(xyz2)) @ WV^T   (pos-hidden in-register)
    fuse_pv<<<dim3(128, 4), 512, 0, stream>>>(xyz2, pos_w1, pos_b1, WP2, pos_b2,
                                              F2T, WV, VB);
    // 5. K = elu(F2T @ WK^T)+1, fused Ksum
    kgemm_kernel<<<dim3(128, 2, 4), 256, 0, stream>>>(WK, F2T, KB, KS);
    // 6. KV
    kv_kernel<<<dim3(16, 8, 4), 256, 0, stream>>>(KB, VB, KV);
    // 7. msg1 = LN1(((elu(F1T@WQ^T)+1) . KV . Z) @ WM^T)
    qattn<<<dim3(128, 4), 512, 0, stream>>>(F1T, WQ, KV, KS, WM, ln1_g, ln1_b, MSG1);
    // 8. out = LN2(relu([F1T|MSG1] @ W1^T) @ W2^T), stored [B, 256, N] fp32
    mlp_fused<<<dim3(256, 4), 512, 0, stream>>>(F1T, MSG1, W1, W2, ln2_g, ln2_b, outp);
    (void)in_sizes; (void)n_in; (void)out_size;
}